// Round 3
// baseline (567.307 us; speedup 1.0000x reference)
//
#include <hip/hip_runtime.h>
#include <math.h>

// ---------------------------------------------------------------------------
// GATEncoder: 2x (GATConv(H=2,C=128) + exact GELU) + final projection.
// GEMMs: split-bf16 MFMA (hi/lo, 3 passes -> ~fp32 accuracy).
// Aggregation: CSR-by-dst; pass A = per-edge softmax weights (parallel exact
// max + sum), pass B = pure weighted gather with batched (src,w) broadcast.
// ---------------------------------------------------------------------------

#define NEG_SLOPE 0.2f

typedef __attribute__((ext_vector_type(8))) short bf16x8;
typedef __attribute__((ext_vector_type(8))) ushort u16x8;
typedef __attribute__((ext_vector_type(4))) float f32x4;

__device__ __forceinline__ void split_f32(float x, ushort& h, ushort& l)
{
    unsigned b = __float_as_uint(x);
    h = (ushort)(b >> 16);
    float xh = __uint_as_float(b & 0xffff0000u);
    l = (ushort)(__float_as_uint(x - xh) >> 16);
}

__device__ __forceinline__ float lrelu(float x)
{
    return x > 0.f ? x : NEG_SLOPE * x;
}

__device__ __forceinline__ float gelu_exact(float x)
{
    return 0.5f * x * (1.0f + erff(x * 0.7071067811865476f));
}

// ------------- weight prep: W[K][N] fp32 -> Bt_hi/Bt_lo [N][K] bf16 --------
__global__ __launch_bounds__(256)
void split_w_kernel(const float* __restrict__ W, ushort* __restrict__ Bth,
                    ushort* __restrict__ Btl, int K, int N)
{
    int t = blockIdx.x * 256 + threadIdx.x;
    if (t >= K * N) return;
    int k = t / N, n = t - k * N;
    ushort h, l;
    split_f32(W[t], h, l);
    Bth[(size_t)n * K + k] = h;
    Btl[(size_t)n * K + k] = l;
}

// ---------------- split-bf16 MFMA GEMM: C = A @ B (+bias) ------------------
__global__ __launch_bounds__(256)
void mfma_gemm(const float* __restrict__ A,
               const ushort* __restrict__ Bth, const ushort* __restrict__ Btl,
               const float* __restrict__ bias,
               float* __restrict__ C, int M, int N, int K)
{
    __shared__ ushort Ah[4][128][8];
    __shared__ ushort Al[4][128][8];
    __shared__ ushort Bh[4][128][8];
    __shared__ ushort Bl[4][128][8];

    const int tid = threadIdx.x;
    const int r0 = blockIdx.y * 128;
    const int c0 = blockIdx.x * 128;
    const int w = tid >> 6, lane = tid & 63;
    const int wr = (w >> 1) * 64, wc = (w & 1) * 64;
    const int lr = lane & 15, kb = lane >> 4;

    const int sr = tid >> 1;
    const int sh = tid & 1;
    const int p0 = sh * 2, p1 = sh * 2 + 1;

    f32x4 acc[4][4] = {};

    for (int kk = 0; kk < K; kk += 32) {
        {
            const int row = r0 + sr;
            float4 v0, v1, v2, v3;
            if (row < M) {
                const float* p = A + (size_t)row * K + kk + sh * 16;
                v0 = *(const float4*)(p);
                v1 = *(const float4*)(p + 4);
                v2 = *(const float4*)(p + 8);
                v3 = *(const float4*)(p + 12);
            } else {
                v0 = v1 = v2 = v3 = make_float4(0.f, 0.f, 0.f, 0.f);
            }
            float v[16] = {v0.x, v0.y, v0.z, v0.w, v1.x, v1.y, v1.z, v1.w,
                           v2.x, v2.y, v2.z, v2.w, v3.x, v3.y, v3.z, v3.w};
            u16x8 h0, h1, l0, l1;
#pragma unroll
            for (int i = 0; i < 8; ++i) {
                ushort hh, ll;
                split_f32(v[i], hh, ll);     h0[i] = hh; l0[i] = ll;
                split_f32(v[8 + i], hh, ll); h1[i] = hh; l1[i] = ll;
            }
            *(u16x8*)&Ah[p0][sr][0] = h0;
            *(u16x8*)&Ah[p1][sr][0] = h1;
            *(u16x8*)&Al[p0][sr][0] = l0;
            *(u16x8*)&Al[p1][sr][0] = l1;
        }
        {
            const ushort* ph = Bth + (size_t)(c0 + sr) * K + kk + sh * 16;
            const ushort* pl = Btl + (size_t)(c0 + sr) * K + kk + sh * 16;
            *(u16x8*)&Bh[p0][sr][0] = *(const u16x8*)(ph);
            *(u16x8*)&Bh[p1][sr][0] = *(const u16x8*)(ph + 8);
            *(u16x8*)&Bl[p0][sr][0] = *(const u16x8*)(pl);
            *(u16x8*)&Bl[p1][sr][0] = *(const u16x8*)(pl + 8);
        }
        __syncthreads();

        bf16x8 ah[4], al[4], bh[4], bl[4];
#pragma unroll
        for (int m = 0; m < 4; ++m) {
            ah[m] = *(const bf16x8*)&Ah[kb][wr + m * 16 + lr][0];
            al[m] = *(const bf16x8*)&Al[kb][wr + m * 16 + lr][0];
        }
#pragma unroll
        for (int n = 0; n < 4; ++n) {
            bh[n] = *(const bf16x8*)&Bh[kb][wc + n * 16 + lr][0];
            bl[n] = *(const bf16x8*)&Bl[kb][wc + n * 16 + lr][0];
        }
#pragma unroll
        for (int m = 0; m < 4; ++m)
#pragma unroll
            for (int n = 0; n < 4; ++n) {
                acc[m][n] = __builtin_amdgcn_mfma_f32_16x16x32_bf16(ah[m], bh[n], acc[m][n], 0, 0, 0);
                acc[m][n] = __builtin_amdgcn_mfma_f32_16x16x32_bf16(ah[m], bl[n], acc[m][n], 0, 0, 0);
                acc[m][n] = __builtin_amdgcn_mfma_f32_16x16x32_bf16(al[m], bh[n], acc[m][n], 0, 0, 0);
            }
        __syncthreads();
    }

#pragma unroll
    for (int n = 0; n < 4; ++n) {
        const int col = c0 + wc + n * 16 + lr;
        const float bv = bias ? bias[col] : 0.f;
#pragma unroll
        for (int m = 0; m < 4; ++m) {
            const int rowb = r0 + wr + m * 16 + kb * 4;
#pragma unroll
            for (int j = 0; j < 4; ++j) {
                const int row = rowb + j;
                if (row < M) C[(size_t)row * N + col] = acc[m][n][j] + bv;
            }
        }
    }
}

// ------------- per-node attention coefficients a_src, a_dst ----------------
__global__ __launch_bounds__(256)
void compute_ab_kernel(const float* __restrict__ xl,
                       const float* __restrict__ att_s,
                       const float* __restrict__ att_d,
                       float* __restrict__ a_s, float* __restrict__ a_d, int n)
{
    const int wave = threadIdx.x >> 6;
    const int lane = threadIdx.x & 63;
    const int v = blockIdx.x * 4 + wave;
    if (v >= n) return;
    const int idx = lane << 2;
    float4 xv = *(const float4*)(xl + (size_t)v * 256 + idx);
    float4 s4 = *(const float4*)(att_s + idx);
    float4 d4 = *(const float4*)(att_d + idx);
    float ps = xv.x * s4.x + xv.y * s4.y + xv.z * s4.z + xv.w * s4.w;
    float pd = xv.x * d4.x + xv.y * d4.y + xv.z * d4.z + xv.w * d4.w;
#pragma unroll
    for (int off = 1; off < 32; off <<= 1) {
        ps += __shfl_xor(ps, off, 64);
        pd += __shfl_xor(pd, off, 64);
    }
    if ((lane & 31) == 0) {
        a_s[v * 2 + (lane >> 5)] = ps;
        a_d[v * 2 + (lane >> 5)] = pd;
    }
}

// --------- pass A: per-edge softmax weights + per-node (w_self, inv) -------
// one wave per node; lanes 0-31 head0 over edges beg+0,1,..; lanes 32-63
// head1 over the same edges. Two phases: exact max, then w=exp(e-m)+sum.
__global__ __launch_bounds__(256)
void edge_alpha_kernel(const float* __restrict__ a_s,
                       const float* __restrict__ a_d,
                       const int* __restrict__ rowptr,
                       const int* __restrict__ esrc,
                       float* __restrict__ walpha,   // [E][2]
                       float* __restrict__ nodeP,    // [N][4]: ws0,inv0,ws1,inv1
                       int n)
{
    const int wave = threadIdx.x >> 6;
    const int lane = threadIdx.x & 63;
    const int v = blockIdx.x * 4 + wave;
    if (v >= n) return;
    const int h = lane >> 5;
    const int j0 = lane & 31;

    const float adv = a_d[v * 2 + h];
    const float e0 = lrelu(a_s[v * 2 + h] + adv);
    const int beg = rowptr[v], end = rowptr[v + 1];

    // phase 1: exact max
    float m = e0;
    for (int i = beg + j0; i < end; i += 32) {
        const int src = esrc[i];
        m = fmaxf(m, lrelu(a_s[src * 2 + h] + adv));
    }
#pragma unroll
    for (int off = 1; off < 32; off <<= 1)
        m = fmaxf(m, __shfl_xor(m, off, 64));

    // phase 2: weights + denom
    float ssum = (j0 == 0) ? __expf(e0 - m) : 0.f;
    for (int i = beg + j0; i < end; i += 32) {
        const int src = esrc[i];
        const float wgt = __expf(lrelu(a_s[src * 2 + h] + adv) - m);
        walpha[(size_t)i * 2 + h] = wgt;
        ssum += wgt;
    }
#pragma unroll
    for (int off = 1; off < 32; off <<= 1)
        ssum += __shfl_xor(ssum, off, 64);

    if (j0 == 0) {
        float2 p;
        p.x = __expf(e0 - m);              // w_self
        p.y = 1.0f / (ssum + 1e-16f);      // inv denom
        *(float2*)(nodeP + (size_t)v * 4 + h * 2) = p;
    }
}

// --------- pass B: pure weighted gather + head-mean + bias + GELU ----------
// one wave per node; batch-load 64 (src,w) pairs, __shfl-broadcast, FMA.
__global__ __launch_bounds__(256)
void gat_gather_kernel(const float* __restrict__ xl,
                       const int* __restrict__ rowptr,
                       const int* __restrict__ esrc,
                       const float* __restrict__ walpha,
                       const float* __restrict__ nodeP,
                       const float* __restrict__ bias,
                       float* __restrict__ out, int n)
{
    const int wave = threadIdx.x >> 6;
    const int lane = threadIdx.x & 63;
    const int v = blockIdx.x * 4 + wave;
    if (v >= n) return;
    const int h = lane >> 5;

    const float2 p = *(const float2*)(nodeP + (size_t)v * 4 + h * 2);
    const float4 xv = *(const float4*)(xl + (size_t)v * 256 + (lane << 2));
    float4 acc0, acc1;
    acc0.x = p.x * xv.x; acc0.y = p.x * xv.y;
    acc0.z = p.x * xv.z; acc0.w = p.x * xv.w;
    acc1 = make_float4(0.f, 0.f, 0.f, 0.f);

    const int beg = rowptr[v], end = rowptr[v + 1];
    for (int i = beg; i < end; i += 64) {
        const int cnt = min(64, end - i);
        int myidx = 0;
        float2 myw = make_float2(0.f, 0.f);
        if (lane < cnt) {
            myidx = esrc[i + lane];
            myw = *(const float2*)(walpha + (size_t)(i + lane) * 2);
        }
#pragma unroll 2
        for (int j = 0; j < cnt; ++j) {
            const int src = __shfl(myidx, j, 64);
            const float wx = __shfl(myw.x, j, 64);
            const float wy = __shfl(myw.y, j, 64);
            const float wgt = h ? wy : wx;
            const float4 xs = *(const float4*)(xl + (size_t)src * 256 + (lane << 2));
            if (j & 1) {
                acc1.x += wgt * xs.x; acc1.y += wgt * xs.y;
                acc1.z += wgt * xs.z; acc1.w += wgt * xs.w;
            } else {
                acc0.x += wgt * xs.x; acc0.y += wgt * xs.y;
                acc0.z += wgt * xs.z; acc0.w += wgt * xs.w;
            }
        }
    }

    float4 r;
    r.x = (acc0.x + acc1.x) * p.y;
    r.y = (acc0.y + acc1.y) * p.y;
    r.z = (acc0.z + acc1.z) * p.y;
    r.w = (acc0.w + acc1.w) * p.y;
    float4 o;
    o.x = 0.5f * (r.x + __shfl_xor(r.x, 32, 64));
    o.y = 0.5f * (r.y + __shfl_xor(r.y, 32, 64));
    o.z = 0.5f * (r.z + __shfl_xor(r.z, 32, 64));
    o.w = 0.5f * (r.w + __shfl_xor(r.w, 32, 64));
    if (lane < 32) {
        float4 bb = *(const float4*)(bias + (lane << 2));
        o.x = gelu_exact(o.x + bb.x);
        o.y = gelu_exact(o.y + bb.y);
        o.z = gelu_exact(o.z + bb.z);
        o.w = gelu_exact(o.w + bb.w);
        *(float4*)(out + (size_t)v * 128 + (lane << 2)) = o;
    }
}

// ---------------------- CSR build (by dst) ---------------------------------
__global__ __launch_bounds__(256)
void hist_kernel(const int* __restrict__ ei, int* __restrict__ cnt, int E)
{
    int e = blockIdx.x * 256 + threadIdx.x;
    if (e < E) atomicAdd(&cnt[ei[E + e]], 1);
}

// single block, 1024 threads, chunk-per-thread + wave shfl scan
__global__ __launch_bounds__(1024)
void scan_kernel(const int* __restrict__ cnt, int* __restrict__ ptr, int n)
{
    const int tid = threadIdx.x;
    const int lane = tid & 63, wid = tid >> 6;
    const int C = (n + 1023) / 1024;
    const int base = tid * C;

    int s = 0;
    for (int k = 0; k < C; ++k)
        if (base + k < n) s += cnt[base + k];

    // inclusive wave scan
    int pre = s;
#pragma unroll
    for (int off = 1; off < 64; off <<= 1) {
        int t = __shfl_up(pre, off, 64);
        if (lane >= off) pre += t;
    }
    __shared__ int wsum[16];
    if (lane == 63) wsum[wid] = pre;
    __syncthreads();
    if (tid == 0) {
        int run = 0;
#pragma unroll
        for (int w2 = 0; w2 < 16; ++w2) {
            int t = wsum[w2]; wsum[w2] = run; run += t;
        }
    }
    __syncthreads();
    int run = pre - s + wsum[wid];   // exclusive prefix for this chunk

    for (int k = 0; k < C; ++k)
        if (base + k < n) { ptr[base + k] = run; run += cnt[base + k]; }
    if (tid == 1023) ptr[n] = run;
}

__global__ __launch_bounds__(256)
void scatter_kernel(const int* __restrict__ ei, const int* __restrict__ ptr,
                    int* __restrict__ cnt, int* __restrict__ esrc, int E)
{
    int e = blockIdx.x * 256 + threadIdx.x;
    if (e < E) {
        int dst = ei[E + e];
        int src = ei[e];
        int pos = ptr[dst] + atomicAdd(&cnt[dst], 1);
        esrc[pos] = src;
    }
}

// ---------------------------------------------------------------------------
extern "C" void kernel_launch(void* const* d_in, const int* in_sizes, int n_in,
                              void* d_out, int out_size, void* d_ws, size_t ws_size,
                              hipStream_t stream)
{
    const float* x       = (const float*)d_in[0];
    const int*   ei      = (const int*)d_in[1];
    const float* W0      = (const float*)d_in[2];
    const float* att_s0  = (const float*)d_in[3];
    const float* att_d0  = (const float*)d_in[4];
    const float* b0      = (const float*)d_in[5];
    const float* W1      = (const float*)d_in[6];
    const float* att_s1  = (const float*)d_in[7];
    const float* att_d1  = (const float*)d_in[8];
    const float* b1      = (const float*)d_in[9];
    const float* pw      = (const float*)d_in[10];
    const float* pb      = (const float*)d_in[11];

    const int N = in_sizes[0] / 256;   // 50000
    const int E = in_sizes[1] / 2;     // 800000

    // workspace layout
    float*  xl  = (float*)d_ws;                  // N*256
    float*  h   = xl + (size_t)N * 256;          // N*128
    float*  a_s = h + (size_t)N * 128;           // N*2
    float*  a_d = a_s + (size_t)N * 2;           // N*2
    float*  wal = a_d + (size_t)N * 2;           // E*2
    float*  ndp = wal + (size_t)E * 2;           // N*4
    int*    cnt = (int*)(ndp + (size_t)N * 4);   // N
    int*    ptr = cnt + N;                       // N+1
    int*    esr = ptr + (N + 1);                 // E
    ushort* w0h = (ushort*)(esr + E);            // 256*256
    ushort* w0l = w0h + 256 * 256;
    ushort* w1h = w0l + 256 * 256;               // 128*256
    ushort* w1l = w1h + 128 * 256;
    ushort* pwh = w1l + 128 * 256;               // 128*128
    ushort* pwl = pwh + 128 * 128;

    const int ablk = (N + 3) / 4;
    const int eblk = (E + 255) / 256;
    const dim3 gL0(2, (N + 127) / 128);
    const dim3 gL1(2, (N + 127) / 128);
    const dim3 gPj(1, (N + 127) / 128);

    // ---- weight prep ----
    split_w_kernel<<<(256 * 256 + 255) / 256, 256, 0, stream>>>(W0, w0h, w0l, 256, 256);
    split_w_kernel<<<(128 * 256 + 255) / 256, 256, 0, stream>>>(W1, w1h, w1l, 128, 256);
    split_w_kernel<<<(128 * 128 + 255) / 256, 256, 0, stream>>>(pw, pwh, pwl, 128, 128);

    // ---- CSR build ----
    hipMemsetAsync(cnt, 0, (size_t)N * sizeof(int), stream);
    hist_kernel<<<eblk, 256, 0, stream>>>(ei, cnt, E);
    scan_kernel<<<1, 1024, 0, stream>>>(cnt, ptr, N);
    hipMemsetAsync(cnt, 0, (size_t)N * sizeof(int), stream);
    scatter_kernel<<<eblk, 256, 0, stream>>>(ei, ptr, cnt, esr, E);

    // ---- layer 0 ----
    mfma_gemm<<<gL0, 256, 0, stream>>>(x, w0h, w0l, nullptr, xl, N, 256, 256);
    compute_ab_kernel<<<ablk, 256, 0, stream>>>(xl, att_s0, att_d0, a_s, a_d, N);
    edge_alpha_kernel<<<ablk, 256, 0, stream>>>(a_s, a_d, ptr, esr, wal, ndp, N);
    gat_gather_kernel<<<ablk, 256, 0, stream>>>(xl, ptr, esr, wal, ndp, b0, h, N);

    // ---- layer 1 ----
    mfma_gemm<<<gL1, 256, 0, stream>>>(h, w1h, w1l, nullptr, xl, N, 256, 128);
    compute_ab_kernel<<<ablk, 256, 0, stream>>>(xl, att_s1, att_d1, a_s, a_d, N);
    edge_alpha_kernel<<<ablk, 256, 0, stream>>>(a_s, a_d, ptr, esr, wal, ndp, N);
    gat_gather_kernel<<<ablk, 256, 0, stream>>>(xl, ptr, esr, wal, ndp, b1, h, N);

    // ---- projection ----
    mfma_gemm<<<gPj, 256, 0, stream>>>(h, pwh, pwl, pb, (float*)d_out, N, 128, 128);
}

// Round 4
// 511.715 us; speedup vs baseline: 1.1086x; 1.1086x over previous
//
#include <hip/hip_runtime.h>
#include <math.h>

// ---------------------------------------------------------------------------
// GATEncoder: 2x (GATConv(H=2,C=128) + exact GELU) + final projection.
// GEMMs: split-bf16 MFMA (hi/lo, 3 passes -> ~fp32 accuracy), epilogue writes
//        bf16 xlb (gather source). fp32 xl is never materialized.
// Scores: a_src = x @ (W @ att)  -- exact refactor, fp32 matvec.
// Aggregation: CSR-by-dst; pass A = per-edge softmax weights, pass B = pure
//              weighted gather from bf16 rows (512B/row), unroll-4 MLP.
// ---------------------------------------------------------------------------

#define NEG_SLOPE 0.2f

typedef __attribute__((ext_vector_type(8))) short bf16x8;
typedef __attribute__((ext_vector_type(8))) ushort u16x8;
typedef __attribute__((ext_vector_type(4))) float f32x4;

__device__ __forceinline__ void split_f32(float x, ushort& h, ushort& l)
{
    unsigned b = __float_as_uint(x);
    h = (ushort)(b >> 16);
    float xh = __uint_as_float(b & 0xffff0000u);
    l = (ushort)(__float_as_uint(x - xh) >> 16);
}

__device__ __forceinline__ ushort f32_to_bf16_rne(float x)
{
    unsigned u = __float_as_uint(x);
    return (ushort)((u + 0x7fffu + ((u >> 16) & 1u)) >> 16);
}

__device__ __forceinline__ float bf16_to_f32(ushort u)
{
    return __uint_as_float(((unsigned)u) << 16);
}

__device__ __forceinline__ float lrelu(float x)
{
    return x > 0.f ? x : NEG_SLOPE * x;
}

__device__ __forceinline__ float gelu_exact(float x)
{
    return 0.5f * x * (1.0f + erff(x * 0.7071067811865476f));
}

// ------------- weight prep: W[K][N] fp32 -> Bt_hi/Bt_lo [N][K] bf16 --------
__global__ __launch_bounds__(256)
void split_w_kernel(const float* __restrict__ W, ushort* __restrict__ Bth,
                    ushort* __restrict__ Btl, int K, int N)
{
    int t = blockIdx.x * 256 + threadIdx.x;
    if (t >= K * N) return;
    int k = t / N, n = t - k * N;
    ushort h, l;
    split_f32(W[t], h, l);
    Bth[(size_t)n * K + k] = h;
    Btl[(size_t)n * K + k] = l;
}

// ------- watt prep: watt[k][4] = {Ws@att_s h0, h1, Ws@att_d h0, h1} --------
// grid = K blocks, 256 threads: t -> h = t>>7, c = t&127.
__global__ __launch_bounds__(256)
void watt_prep_kernel(const float* __restrict__ W,      // [K][2*C]
                      const float* __restrict__ att_s,  // [2][C]
                      const float* __restrict__ att_d,  // [2][C]
                      float* __restrict__ watt,         // [K][4]
                      int C, int Nout)
{
    const int k = blockIdx.x;
    const int t = threadIdx.x;
    const int h = t >> 7, c = t & 127;
    const int lane = t & 63, wid = t >> 6;

    float ps = 0.f, pd = 0.f;
    if (c < C) {
        const float w = W[(size_t)k * Nout + h * C + c];
        ps = w * att_s[h * C + c];
        pd = w * att_d[h * C + c];
    }
#pragma unroll
    for (int off = 1; off < 64; off <<= 1) {
        ps += __shfl_xor(ps, off, 64);
        pd += __shfl_xor(pd, off, 64);
    }
    __shared__ float sm[4][2];
    if (lane == 0) { sm[wid][0] = ps; sm[wid][1] = pd; }
    __syncthreads();
    if (t == 0) {
        watt[k * 4 + 0] = sm[0][0] + sm[1][0];  // a_src h0
        watt[k * 4 + 1] = sm[2][0] + sm[3][0];  // a_src h1
        watt[k * 4 + 2] = sm[0][1] + sm[1][1];  // a_dst h0
        watt[k * 4 + 3] = sm[2][1] + sm[3][1];  // a_dst h1
    }
}

// ---- scores: a_s[v][h] = X[v] . watt[:,h], a_d[v][h] = X[v] . watt[:,2+h] --
__global__ __launch_bounds__(256)
void attn_matvec_kernel(const float* __restrict__ X,     // [n][K]
                        const float* __restrict__ watt,  // [K][4]
                        float* __restrict__ a_s, float* __restrict__ a_d,
                        int n, int K)
{
    const int wave = threadIdx.x >> 6;
    const int lane = threadIdx.x & 63;
    const int v = blockIdx.x * 4 + wave;
    if (v >= n) return;

    float s0 = 0.f, s1 = 0.f, d0 = 0.f, d1 = 0.f;
    const int k0 = lane << 2;
    if (k0 < K) {
        const float4 xv = *(const float4*)(X + (size_t)v * K + k0);
        const float x4[4] = {xv.x, xv.y, xv.z, xv.w};
#pragma unroll
        for (int i = 0; i < 4; ++i) {
            const float4 wv = *(const float4*)(watt + (k0 + i) * 4);
            s0 += x4[i] * wv.x;
            s1 += x4[i] * wv.y;
            d0 += x4[i] * wv.z;
            d1 += x4[i] * wv.w;
        }
    }
#pragma unroll
    for (int off = 1; off < 64; off <<= 1) {
        s0 += __shfl_xor(s0, off, 64);
        s1 += __shfl_xor(s1, off, 64);
        d0 += __shfl_xor(d0, off, 64);
        d1 += __shfl_xor(d1, off, 64);
    }
    if (lane == 0) {
        *(float2*)(a_s + (size_t)v * 2) = make_float2(s0, s1);
        *(float2*)(a_d + (size_t)v * 2) = make_float2(d0, d1);
    }
}

// ---------------- split-bf16 MFMA GEMM: C = A @ B (+bias) ------------------
// Outputs: Cf fp32 (nullable), Cb bf16 (nullable).
__global__ __launch_bounds__(256)
void mfma_gemm(const float* __restrict__ A,
               const ushort* __restrict__ Bth, const ushort* __restrict__ Btl,
               const float* __restrict__ bias,
               float* __restrict__ Cf, ushort* __restrict__ Cb,
               int M, int N, int K)
{
    __shared__ ushort Ah[4][128][8];
    __shared__ ushort Al[4][128][8];
    __shared__ ushort Bh[4][128][8];
    __shared__ ushort Bl[4][128][8];

    const int tid = threadIdx.x;
    const int r0 = blockIdx.y * 128;
    const int c0 = blockIdx.x * 128;
    const int w = tid >> 6, lane = tid & 63;
    const int wr = (w >> 1) * 64, wc = (w & 1) * 64;
    const int lr = lane & 15, kb = lane >> 4;

    const int sr = tid >> 1;
    const int sh = tid & 1;
    const int p0 = sh * 2, p1 = sh * 2 + 1;

    f32x4 acc[4][4] = {};

    for (int kk = 0; kk < K; kk += 32) {
        {
            const int row = r0 + sr;
            float4 v0, v1, v2, v3;
            if (row < M) {
                const float* p = A + (size_t)row * K + kk + sh * 16;
                v0 = *(const float4*)(p);
                v1 = *(const float4*)(p + 4);
                v2 = *(const float4*)(p + 8);
                v3 = *(const float4*)(p + 12);
            } else {
                v0 = v1 = v2 = v3 = make_float4(0.f, 0.f, 0.f, 0.f);
            }
            float v[16] = {v0.x, v0.y, v0.z, v0.w, v1.x, v1.y, v1.z, v1.w,
                           v2.x, v2.y, v2.z, v2.w, v3.x, v3.y, v3.z, v3.w};
            u16x8 h0, h1, l0, l1;
#pragma unroll
            for (int i = 0; i < 8; ++i) {
                ushort hh, ll;
                split_f32(v[i], hh, ll);     h0[i] = hh; l0[i] = ll;
                split_f32(v[8 + i], hh, ll); h1[i] = hh; l1[i] = ll;
            }
            *(u16x8*)&Ah[p0][sr][0] = h0;
            *(u16x8*)&Ah[p1][sr][0] = h1;
            *(u16x8*)&Al[p0][sr][0] = l0;
            *(u16x8*)&Al[p1][sr][0] = l1;
        }
        {
            const ushort* ph = Bth + (size_t)(c0 + sr) * K + kk + sh * 16;
            const ushort* pl = Btl + (size_t)(c0 + sr) * K + kk + sh * 16;
            *(u16x8*)&Bh[p0][sr][0] = *(const u16x8*)(ph);
            *(u16x8*)&Bh[p1][sr][0] = *(const u16x8*)(ph + 8);
            *(u16x8*)&Bl[p0][sr][0] = *(const u16x8*)(pl);
            *(u16x8*)&Bl[p1][sr][0] = *(const u16x8*)(pl + 8);
        }
        __syncthreads();

        bf16x8 ah[4], al[4], bh[4], bl[4];
#pragma unroll
        for (int m = 0; m < 4; ++m) {
            ah[m] = *(const bf16x8*)&Ah[kb][wr + m * 16 + lr][0];
            al[m] = *(const bf16x8*)&Al[kb][wr + m * 16 + lr][0];
        }
#pragma unroll
        for (int n = 0; n < 4; ++n) {
            bh[n] = *(const bf16x8*)&Bh[kb][wc + n * 16 + lr][0];
            bl[n] = *(const bf16x8*)&Bl[kb][wc + n * 16 + lr][0];
        }
#pragma unroll
        for (int m = 0; m < 4; ++m)
#pragma unroll
            for (int n = 0; n < 4; ++n) {
                acc[m][n] = __builtin_amdgcn_mfma_f32_16x16x32_bf16(ah[m], bh[n], acc[m][n], 0, 0, 0);
                acc[m][n] = __builtin_amdgcn_mfma_f32_16x16x32_bf16(ah[m], bl[n], acc[m][n], 0, 0, 0);
                acc[m][n] = __builtin_amdgcn_mfma_f32_16x16x32_bf16(al[m], bh[n], acc[m][n], 0, 0, 0);
            }
        __syncthreads();
    }

#pragma unroll
    for (int n = 0; n < 4; ++n) {
        const int col = c0 + wc + n * 16 + lr;
        const float bv = bias ? bias[col] : 0.f;
#pragma unroll
        for (int m = 0; m < 4; ++m) {
            const int rowb = r0 + wr + m * 16 + kb * 4;
#pragma unroll
            for (int j = 0; j < 4; ++j) {
                const int row = rowb + j;
                if (row < M) {
                    const float val = acc[m][n][j] + bv;
                    if (Cf) Cf[(size_t)row * N + col] = val;
                    if (Cb) Cb[(size_t)row * N + col] = f32_to_bf16_rne(val);
                }
            }
        }
    }
}

// --------- pass A: per-edge softmax weights + per-node (w_self, inv) -------
__global__ __launch_bounds__(256)
void edge_alpha_kernel(const float* __restrict__ a_s,
                       const float* __restrict__ a_d,
                       const int* __restrict__ rowptr,
                       const int* __restrict__ esrc,
                       float* __restrict__ walpha,   // [E][2]
                       float* __restrict__ nodeP,    // [N][4]: ws0,inv0,ws1,inv1
                       int n)
{
    const int wave = threadIdx.x >> 6;
    const int lane = threadIdx.x & 63;
    const int v = blockIdx.x * 4 + wave;
    if (v >= n) return;
    const int h = lane >> 5;
    const int j0 = lane & 31;

    const float adv = a_d[v * 2 + h];
    const float e0 = lrelu(a_s[v * 2 + h] + adv);
    const int beg = rowptr[v], end = rowptr[v + 1];

    float m = e0;
    for (int i = beg + j0; i < end; i += 32) {
        const int src = esrc[i];
        m = fmaxf(m, lrelu(a_s[src * 2 + h] + adv));
    }
#pragma unroll
    for (int off = 1; off < 32; off <<= 1)
        m = fmaxf(m, __shfl_xor(m, off, 64));

    float ssum = (j0 == 0) ? __expf(e0 - m) : 0.f;
    for (int i = beg + j0; i < end; i += 32) {
        const int src = esrc[i];
        const float wgt = __expf(lrelu(a_s[src * 2 + h] + adv) - m);
        walpha[(size_t)i * 2 + h] = wgt;
        ssum += wgt;
    }
#pragma unroll
    for (int off = 1; off < 32; off <<= 1)
        ssum += __shfl_xor(ssum, off, 64);

    if (j0 == 0) {
        float2 p;
        p.x = __expf(e0 - m);
        p.y = 1.0f / (ssum + 1e-16f);
        *(float2*)(nodeP + (size_t)v * 4 + h * 2) = p;
    }
}

// --------- pass B: weighted gather (bf16 rows) + head-mean + bias + GELU ---
__global__ __launch_bounds__(256)
void gat_gather_kernel(const ushort* __restrict__ xlb,  // [n][256] bf16
                       const int* __restrict__ rowptr,
                       const int* __restrict__ esrc,
                       const float* __restrict__ walpha,
                       const float* __restrict__ nodeP,
                       const float* __restrict__ bias,
                       float* __restrict__ out, int n)
{
    const int wave = threadIdx.x >> 6;
    const int lane = threadIdx.x & 63;
    const int v = blockIdx.x * 4 + wave;
    if (v >= n) return;
    const int h = lane >> 5;

    const float2 p = *(const float2*)(nodeP + (size_t)v * 4 + h * 2);
    const ushort4 xv4 = *(const ushort4*)(xlb + (size_t)v * 256 + (lane << 2));
    float4 acc0, acc1;
    acc0.x = p.x * bf16_to_f32(xv4.x);
    acc0.y = p.x * bf16_to_f32(xv4.y);
    acc0.z = p.x * bf16_to_f32(xv4.z);
    acc0.w = p.x * bf16_to_f32(xv4.w);
    acc1 = make_float4(0.f, 0.f, 0.f, 0.f);

    const int beg = rowptr[v], end = rowptr[v + 1];
    for (int i = beg; i < end; i += 64) {
        const int cnt = min(64, end - i);
        int myidx = 0;
        float2 myw = make_float2(0.f, 0.f);
        if (lane < cnt) {
            myidx = esrc[i + lane];
            myw = *(const float2*)(walpha + (size_t)(i + lane) * 2);
        }
#pragma unroll 4
        for (int j = 0; j < cnt; ++j) {
            const int src = __shfl(myidx, j, 64);
            const float wx = __shfl(myw.x, j, 64);
            const float wy = __shfl(myw.y, j, 64);
            const float wgt = h ? wy : wx;
            const ushort4 xs4 = *(const ushort4*)(xlb + (size_t)src * 256 + (lane << 2));
            if (j & 1) {
                acc1.x += wgt * bf16_to_f32(xs4.x);
                acc1.y += wgt * bf16_to_f32(xs4.y);
                acc1.z += wgt * bf16_to_f32(xs4.z);
                acc1.w += wgt * bf16_to_f32(xs4.w);
            } else {
                acc0.x += wgt * bf16_to_f32(xs4.x);
                acc0.y += wgt * bf16_to_f32(xs4.y);
                acc0.z += wgt * bf16_to_f32(xs4.z);
                acc0.w += wgt * bf16_to_f32(xs4.w);
            }
        }
    }

    float4 r;
    r.x = (acc0.x + acc1.x) * p.y;
    r.y = (acc0.y + acc1.y) * p.y;
    r.z = (acc0.z + acc1.z) * p.y;
    r.w = (acc0.w + acc1.w) * p.y;
    float4 o;
    o.x = 0.5f * (r.x + __shfl_xor(r.x, 32, 64));
    o.y = 0.5f * (r.y + __shfl_xor(r.y, 32, 64));
    o.z = 0.5f * (r.z + __shfl_xor(r.z, 32, 64));
    o.w = 0.5f * (r.w + __shfl_xor(r.w, 32, 64));
    if (lane < 32) {
        float4 bb = *(const float4*)(bias + (lane << 2));
        o.x = gelu_exact(o.x + bb.x);
        o.y = gelu_exact(o.y + bb.y);
        o.z = gelu_exact(o.z + bb.z);
        o.w = gelu_exact(o.w + bb.w);
        *(float4*)(out + (size_t)v * 128 + (lane << 2)) = o;
    }
}

// ---------------------- CSR build (by dst) ---------------------------------
__global__ __launch_bounds__(256)
void hist_kernel(const int* __restrict__ ei, int* __restrict__ cnt, int E)
{
    int e = blockIdx.x * 256 + threadIdx.x;
    if (e < E) atomicAdd(&cnt[ei[E + e]], 1);
}

__global__ __launch_bounds__(1024)
void scan_kernel(const int* __restrict__ cnt, int* __restrict__ ptr, int n)
{
    const int tid = threadIdx.x;
    const int lane = tid & 63, wid = tid >> 6;
    const int C = (n + 1023) / 1024;
    const int base = tid * C;

    int s = 0;
    for (int k = 0; k < C; ++k)
        if (base + k < n) s += cnt[base + k];

    int pre = s;
#pragma unroll
    for (int off = 1; off < 64; off <<= 1) {
        int t = __shfl_up(pre, off, 64);
        if (lane >= off) pre += t;
    }
    __shared__ int wsum[16];
    if (lane == 63) wsum[wid] = pre;
    __syncthreads();
    if (tid == 0) {
        int run = 0;
#pragma unroll
        for (int w2 = 0; w2 < 16; ++w2) {
            int t = wsum[w2]; wsum[w2] = run; run += t;
        }
    }
    __syncthreads();
    int run = pre - s + wsum[wid];

    for (int k = 0; k < C; ++k)
        if (base + k < n) { ptr[base + k] = run; run += cnt[base + k]; }
    if (tid == 1023) ptr[n] = run;
}

__global__ __launch_bounds__(256)
void scatter_kernel(const int* __restrict__ ei, const int* __restrict__ ptr,
                    int* __restrict__ cnt, int* __restrict__ esrc, int E)
{
    int e = blockIdx.x * 256 + threadIdx.x;
    if (e < E) {
        int dst = ei[E + e];
        int src = ei[e];
        int pos = ptr[dst] + atomicAdd(&cnt[dst], 1);
        esrc[pos] = src;
    }
}

// ---------------------------------------------------------------------------
extern "C" void kernel_launch(void* const* d_in, const int* in_sizes, int n_in,
                              void* d_out, int out_size, void* d_ws, size_t ws_size,
                              hipStream_t stream)
{
    const float* x       = (const float*)d_in[0];
    const int*   ei      = (const int*)d_in[1];
    const float* W0      = (const float*)d_in[2];
    const float* att_s0  = (const float*)d_in[3];
    const float* att_d0  = (const float*)d_in[4];
    const float* b0      = (const float*)d_in[5];
    const float* W1      = (const float*)d_in[6];
    const float* att_s1  = (const float*)d_in[7];
    const float* att_d1  = (const float*)d_in[8];
    const float* b1      = (const float*)d_in[9];
    const float* pw      = (const float*)d_in[10];
    const float* pb      = (const float*)d_in[11];

    const int N = in_sizes[0] / 256;   // 50000
    const int E = in_sizes[1] / 2;     // 800000

    // workspace layout
    ushort* xlb = (ushort*)d_ws;                  // N*256 bf16
    float*  h   = (float*)(xlb + (size_t)N * 256);// N*128 fp32
    float*  a_s = h + (size_t)N * 128;            // N*2
    float*  a_d = a_s + (size_t)N * 2;            // N*2
    float*  wal = a_d + (size_t)N * 2;            // E*2
    float*  ndp = wal + (size_t)E * 2;            // N*4
    float*  wt0 = ndp + (size_t)N * 4;            // 256*4
    float*  wt1 = wt0 + 256 * 4;                  // 128*4
    int*    cnt = (int*)(wt1 + 128 * 4);          // N
    int*    ptr = cnt + N;                        // N+1
    int*    esr = ptr + (N + 1);                  // E
    ushort* w0h = (ushort*)(esr + E);             // 256*256
    ushort* w0l = w0h + 256 * 256;
    ushort* w1h = w0l + 256 * 256;                // 128*256
    ushort* w1l = w1h + 128 * 256;
    ushort* pwh = w1l + 128 * 256;                // 128*128
    ushort* pwl = pwh + 128 * 128;

    const int ablk = (N + 3) / 4;
    const int eblk = (E + 255) / 256;
    const dim3 gL0(2, (N + 127) / 128);
    const dim3 gL1(2, (N + 127) / 128);
    const dim3 gPj(1, (N + 127) / 128);

    // ---- weight prep ----
    split_w_kernel<<<(256 * 256 + 255) / 256, 256, 0, stream>>>(W0, w0h, w0l, 256, 256);
    split_w_kernel<<<(128 * 256 + 255) / 256, 256, 0, stream>>>(W1, w1h, w1l, 128, 256);
    split_w_kernel<<<(128 * 128 + 255) / 256, 256, 0, stream>>>(pw, pwh, pwl, 128, 128);
    watt_prep_kernel<<<256, 256, 0, stream>>>(W0, att_s0, att_d0, wt0, 128, 256);
    watt_prep_kernel<<<128, 256, 0, stream>>>(W1, att_s1, att_d1, wt1, 128, 256);

    // ---- CSR build ----
    hipMemsetAsync(cnt, 0, (size_t)N * sizeof(int), stream);
    hist_kernel<<<eblk, 256, 0, stream>>>(ei, cnt, E);
    scan_kernel<<<1, 1024, 0, stream>>>(cnt, ptr, N);
    hipMemsetAsync(cnt, 0, (size_t)N * sizeof(int), stream);
    scatter_kernel<<<eblk, 256, 0, stream>>>(ei, ptr, cnt, esr, E);

    // ---- layer 0 ----
    mfma_gemm<<<gL0, 256, 0, stream>>>(x, w0h, w0l, nullptr, nullptr, xlb, N, 256, 256);
    attn_matvec_kernel<<<ablk, 256, 0, stream>>>(x, wt0, a_s, a_d, N, 256);
    edge_alpha_kernel<<<ablk, 256, 0, stream>>>(a_s, a_d, ptr, esr, wal, ndp, N);
    gat_gather_kernel<<<ablk, 256, 0, stream>>>(xlb, ptr, esr, wal, ndp, b0, h, N);

    // ---- layer 1 ----
    mfma_gemm<<<gL1, 256, 0, stream>>>(h, w1h, w1l, nullptr, nullptr, xlb, N, 256, 128);
    attn_matvec_kernel<<<ablk, 256, 0, stream>>>(h, wt1, a_s, a_d, N, 128);
    edge_alpha_kernel<<<ablk, 256, 0, stream>>>(a_s, a_d, ptr, esr, wal, ndp, N);
    gat_gather_kernel<<<ablk, 256, 0, stream>>>(xlb, ptr, esr, wal, ndp, b1, h, N);

    // ---- projection ----
    mfma_gemm<<<gPj, 256, 0, stream>>>(h, pwh, pwl, pb, (float*)d_out, nullptr, N, 128, 128);
}

// Round 6
// 430.071 us; speedup vs baseline: 1.3191x; 1.1898x over previous
//
#include <hip/hip_runtime.h>
#include <math.h>

// ---------------------------------------------------------------------------
// GATEncoder: 2x (GATConv(H=2,C=128) + exact GELU) + final projection.
// GEMMs: split-bf16 MFMA (hi/lo, 3 passes -> ~fp32 accuracy), epilogue writes
//        bf16 xlb (gather source). fp32 xl is never materialized.
// Scores: a_src = x @ (W @ att)  -- exact refactor, fp32 matvec.
// Aggregation: CSR-by-dst; pass A = per-edge softmax weights, pass B = pure
//              weighted gather from bf16 rows (512B/row), unroll-4 MLP.
// CSR scan: hierarchical, Hillis-Steele LDS inner pattern (rounds-1..3-proven).
// ---------------------------------------------------------------------------

#define NEG_SLOPE 0.2f

typedef __attribute__((ext_vector_type(8))) short bf16x8;
typedef __attribute__((ext_vector_type(8))) ushort u16x8;
typedef __attribute__((ext_vector_type(4))) float f32x4;

__device__ __forceinline__ void split_f32(float x, ushort& h, ushort& l)
{
    unsigned b = __float_as_uint(x);
    h = (ushort)(b >> 16);
    float xh = __uint_as_float(b & 0xffff0000u);
    l = (ushort)(__float_as_uint(x - xh) >> 16);
}

__device__ __forceinline__ ushort f32_to_bf16_rne(float x)
{
    unsigned u = __float_as_uint(x);
    return (ushort)((u + 0x7fffu + ((u >> 16) & 1u)) >> 16);
}

__device__ __forceinline__ float bf16_to_f32(ushort u)
{
    return __uint_as_float(((unsigned)u) << 16);
}

__device__ __forceinline__ float lrelu(float x)
{
    return x > 0.f ? x : NEG_SLOPE * x;
}

__device__ __forceinline__ float gelu_exact(float x)
{
    return 0.5f * x * (1.0f + erff(x * 0.7071067811865476f));
}

// ------------- weight prep: W[K][N] fp32 -> Bt_hi/Bt_lo [N][K] bf16 --------
__global__ __launch_bounds__(256)
void split_w_kernel(const float* __restrict__ W, ushort* __restrict__ Bth,
                    ushort* __restrict__ Btl, int K, int N)
{
    int t = blockIdx.x * 256 + threadIdx.x;
    if (t >= K * N) return;
    int k = t / N, n = t - k * N;
    ushort h, l;
    split_f32(W[t], h, l);
    Bth[(size_t)n * K + k] = h;
    Btl[(size_t)n * K + k] = l;
}

// ------- watt prep: watt[k][4] = {Ws@att_s h0, h1, Ws@att_d h0, h1} --------
__global__ __launch_bounds__(256)
void watt_prep_kernel(const float* __restrict__ W,      // [K][2*C]
                      const float* __restrict__ att_s,  // [2][C]
                      const float* __restrict__ att_d,  // [2][C]
                      float* __restrict__ watt,         // [K][4]
                      int C, int Nout)
{
    const int k = blockIdx.x;
    const int t = threadIdx.x;
    const int h = t >> 7, c = t & 127;
    const int lane = t & 63, wid = t >> 6;

    float ps = 0.f, pd = 0.f;
    if (c < C) {
        const float w = W[(size_t)k * Nout + h * C + c];
        ps = w * att_s[h * C + c];
        pd = w * att_d[h * C + c];
    }
#pragma unroll
    for (int off = 1; off < 64; off <<= 1) {
        ps += __shfl_xor(ps, off, 64);
        pd += __shfl_xor(pd, off, 64);
    }
    __shared__ float sm[4][2];
    if (lane == 0) { sm[wid][0] = ps; sm[wid][1] = pd; }
    __syncthreads();
    if (t == 0) {
        watt[k * 4 + 0] = sm[0][0] + sm[1][0];
        watt[k * 4 + 1] = sm[2][0] + sm[3][0];
        watt[k * 4 + 2] = sm[0][1] + sm[1][1];
        watt[k * 4 + 3] = sm[2][1] + sm[3][1];
    }
}

// ---- scores: a_s[v][h] = X[v] . watt[:,h], a_d[v][h] = X[v] . watt[:,2+h] --
__global__ __launch_bounds__(256)
void attn_matvec_kernel(const float* __restrict__ X,     // [n][K]
                        const float* __restrict__ watt,  // [K][4]
                        float* __restrict__ a_s, float* __restrict__ a_d,
                        int n, int K)
{
    const int wave = threadIdx.x >> 6;
    const int lane = threadIdx.x & 63;
    const int v = blockIdx.x * 4 + wave;
    if (v >= n) return;

    float s0 = 0.f, s1 = 0.f, d0 = 0.f, d1 = 0.f;
    const int k0 = lane << 2;
    if (k0 < K) {
        const float4 xv = *(const float4*)(X + (size_t)v * K + k0);
        const float x4[4] = {xv.x, xv.y, xv.z, xv.w};
#pragma unroll
        for (int i = 0; i < 4; ++i) {
            const float4 wv = *(const float4*)(watt + (k0 + i) * 4);
            s0 += x4[i] * wv.x;
            s1 += x4[i] * wv.y;
            d0 += x4[i] * wv.z;
            d1 += x4[i] * wv.w;
        }
    }
#pragma unroll
    for (int off = 1; off < 64; off <<= 1) {
        s0 += __shfl_xor(s0, off, 64);
        s1 += __shfl_xor(s1, off, 64);
        d0 += __shfl_xor(d0, off, 64);
        d1 += __shfl_xor(d1, off, 64);
    }
    if (lane == 0) {
        *(float2*)(a_s + (size_t)v * 2) = make_float2(s0, s1);
        *(float2*)(a_d + (size_t)v * 2) = make_float2(d0, d1);
    }
}

// ---------------- split-bf16 MFMA GEMM: C = A @ B (+bias) ------------------
__global__ __launch_bounds__(256)
void mfma_gemm(const float* __restrict__ A,
               const ushort* __restrict__ Bth, const ushort* __restrict__ Btl,
               const float* __restrict__ bias,
               float* __restrict__ Cf, ushort* __restrict__ Cb,
               int M, int N, int K)
{
    __shared__ ushort Ah[4][128][8];
    __shared__ ushort Al[4][128][8];
    __shared__ ushort Bh[4][128][8];
    __shared__ ushort Bl[4][128][8];

    const int tid = threadIdx.x;
    const int r0 = blockIdx.y * 128;
    const int c0 = blockIdx.x * 128;
    const int w = tid >> 6, lane = tid & 63;
    const int wr = (w >> 1) * 64, wc = (w & 1) * 64;
    const int lr = lane & 15, kb = lane >> 4;

    const int sr = tid >> 1;
    const int sh = tid & 1;
    const int p0 = sh * 2, p1 = sh * 2 + 1;

    f32x4 acc[4][4] = {};

    for (int kk = 0; kk < K; kk += 32) {
        {
            const int row = r0 + sr;
            float4 v0, v1, v2, v3;
            if (row < M) {
                const float* p = A + (size_t)row * K + kk + sh * 16;
                v0 = *(const float4*)(p);
                v1 = *(const float4*)(p + 4);
                v2 = *(const float4*)(p + 8);
                v3 = *(const float4*)(p + 12);
            } else {
                v0 = v1 = v2 = v3 = make_float4(0.f, 0.f, 0.f, 0.f);
            }
            float v[16] = {v0.x, v0.y, v0.z, v0.w, v1.x, v1.y, v1.z, v1.w,
                           v2.x, v2.y, v2.z, v2.w, v3.x, v3.y, v3.z, v3.w};
            u16x8 h0, h1, l0, l1;
#pragma unroll
            for (int i = 0; i < 8; ++i) {
                ushort hh, ll;
                split_f32(v[i], hh, ll);     h0[i] = hh; l0[i] = ll;
                split_f32(v[8 + i], hh, ll); h1[i] = hh; l1[i] = ll;
            }
            *(u16x8*)&Ah[p0][sr][0] = h0;
            *(u16x8*)&Ah[p1][sr][0] = h1;
            *(u16x8*)&Al[p0][sr][0] = l0;
            *(u16x8*)&Al[p1][sr][0] = l1;
        }
        {
            const ushort* ph = Bth + (size_t)(c0 + sr) * K + kk + sh * 16;
            const ushort* pl = Btl + (size_t)(c0 + sr) * K + kk + sh * 16;
            *(u16x8*)&Bh[p0][sr][0] = *(const u16x8*)(ph);
            *(u16x8*)&Bh[p1][sr][0] = *(const u16x8*)(ph + 8);
            *(u16x8*)&Bl[p0][sr][0] = *(const u16x8*)(pl);
            *(u16x8*)&Bl[p1][sr][0] = *(const u16x8*)(pl + 8);
        }
        __syncthreads();

        bf16x8 ah[4], al[4], bh[4], bl[4];
#pragma unroll
        for (int m = 0; m < 4; ++m) {
            ah[m] = *(const bf16x8*)&Ah[kb][wr + m * 16 + lr][0];
            al[m] = *(const bf16x8*)&Al[kb][wr + m * 16 + lr][0];
        }
#pragma unroll
        for (int n = 0; n < 4; ++n) {
            bh[n] = *(const bf16x8*)&Bh[kb][wc + n * 16 + lr][0];
            bl[n] = *(const bf16x8*)&Bl[kb][wc + n * 16 + lr][0];
        }
#pragma unroll
        for (int m = 0; m < 4; ++m)
#pragma unroll
            for (int n = 0; n < 4; ++n) {
                acc[m][n] = __builtin_amdgcn_mfma_f32_16x16x32_bf16(ah[m], bh[n], acc[m][n], 0, 0, 0);
                acc[m][n] = __builtin_amdgcn_mfma_f32_16x16x32_bf16(ah[m], bl[n], acc[m][n], 0, 0, 0);
                acc[m][n] = __builtin_amdgcn_mfma_f32_16x16x32_bf16(al[m], bh[n], acc[m][n], 0, 0, 0);
            }
        __syncthreads();
    }

#pragma unroll
    for (int n = 0; n < 4; ++n) {
        const int col = c0 + wc + n * 16 + lr;
        const float bv = bias ? bias[col] : 0.f;
#pragma unroll
        for (int m = 0; m < 4; ++m) {
            const int rowb = r0 + wr + m * 16 + kb * 4;
#pragma unroll
            for (int j = 0; j < 4; ++j) {
                const int row = rowb + j;
                if (row < M) {
                    const float val = acc[m][n][j] + bv;
                    if (Cf) Cf[(size_t)row * N + col] = val;
                    if (Cb) Cb[(size_t)row * N + col] = f32_to_bf16_rne(val);
                }
            }
        }
    }
}

// --------- pass A: per-edge softmax weights + per-node (w_self, inv) -------
__global__ __launch_bounds__(256)
void edge_alpha_kernel(const float* __restrict__ a_s,
                       const float* __restrict__ a_d,
                       const int* __restrict__ rowptr,
                       const int* __restrict__ esrc,
                       float* __restrict__ walpha,   // [E][2]
                       float* __restrict__ nodeP,    // [N][4]
                       int n)
{
    const int wave = threadIdx.x >> 6;
    const int lane = threadIdx.x & 63;
    const int v = blockIdx.x * 4 + wave;
    if (v >= n) return;
    const int h = lane >> 5;
    const int j0 = lane & 31;

    const float adv = a_d[v * 2 + h];
    const float e0 = lrelu(a_s[v * 2 + h] + adv);
    const int beg = rowptr[v], end = rowptr[v + 1];

    float m = e0;
    for (int i = beg + j0; i < end; i += 32) {
        const int src = esrc[i];
        m = fmaxf(m, lrelu(a_s[src * 2 + h] + adv));
    }
#pragma unroll
    for (int off = 1; off < 32; off <<= 1)
        m = fmaxf(m, __shfl_xor(m, off, 64));

    float ssum = (j0 == 0) ? __expf(e0 - m) : 0.f;
    for (int i = beg + j0; i < end; i += 32) {
        const int src = esrc[i];
        const float wgt = __expf(lrelu(a_s[src * 2 + h] + adv) - m);
        walpha[(size_t)i * 2 + h] = wgt;
        ssum += wgt;
    }
#pragma unroll
    for (int off = 1; off < 32; off <<= 1)
        ssum += __shfl_xor(ssum, off, 64);

    if (j0 == 0) {
        float2 p;
        p.x = __expf(e0 - m);
        p.y = 1.0f / (ssum + 1e-16f);
        *(float2*)(nodeP + (size_t)v * 4 + h * 2) = p;
    }
}

// --------- pass B: weighted gather (bf16 rows) + head-mean + bias + GELU ---
__global__ __launch_bounds__(256)
void gat_gather_kernel(const ushort* __restrict__ xlb,  // [n][256] bf16
                       const int* __restrict__ rowptr,
                       const int* __restrict__ esrc,
                       const float* __restrict__ walpha,
                       const float* __restrict__ nodeP,
                       const float* __restrict__ bias,
                       float* __restrict__ out, int n)
{
    const int wave = threadIdx.x >> 6;
    const int lane = threadIdx.x & 63;
    const int v = blockIdx.x * 4 + wave;
    if (v >= n) return;
    const int h = lane >> 5;

    const float2 p = *(const float2*)(nodeP + (size_t)v * 4 + h * 2);
    const ushort4 xv4 = *(const ushort4*)(xlb + (size_t)v * 256 + (lane << 2));
    float4 acc0, acc1;
    acc0.x = p.x * bf16_to_f32(xv4.x);
    acc0.y = p.x * bf16_to_f32(xv4.y);
    acc0.z = p.x * bf16_to_f32(xv4.z);
    acc0.w = p.x * bf16_to_f32(xv4.w);
    acc1 = make_float4(0.f, 0.f, 0.f, 0.f);

    const int beg = rowptr[v], end = rowptr[v + 1];
    for (int i = beg; i < end; i += 64) {
        const int cnt = min(64, end - i);
        int myidx = 0;
        float2 myw = make_float2(0.f, 0.f);
        if (lane < cnt) {
            myidx = esrc[i + lane];
            myw = *(const float2*)(walpha + (size_t)(i + lane) * 2);
        }
#pragma unroll 4
        for (int j = 0; j < cnt; ++j) {
            const int src = __shfl(myidx, j, 64);
            const float wx = __shfl(myw.x, j, 64);
            const float wy = __shfl(myw.y, j, 64);
            const float wgt = h ? wy : wx;
            const ushort4 xs4 = *(const ushort4*)(xlb + (size_t)src * 256 + (lane << 2));
            if (j & 1) {
                acc1.x += wgt * bf16_to_f32(xs4.x);
                acc1.y += wgt * bf16_to_f32(xs4.y);
                acc1.z += wgt * bf16_to_f32(xs4.z);
                acc1.w += wgt * bf16_to_f32(xs4.w);
            } else {
                acc0.x += wgt * bf16_to_f32(xs4.x);
                acc0.y += wgt * bf16_to_f32(xs4.y);
                acc0.z += wgt * bf16_to_f32(xs4.z);
                acc0.w += wgt * bf16_to_f32(xs4.w);
            }
        }
    }

    float4 r;
    r.x = (acc0.x + acc1.x) * p.y;
    r.y = (acc0.y + acc1.y) * p.y;
    r.z = (acc0.z + acc1.z) * p.y;
    r.w = (acc0.w + acc1.w) * p.y;
    float4 o;
    o.x = 0.5f * (r.x + __shfl_xor(r.x, 32, 64));
    o.y = 0.5f * (r.y + __shfl_xor(r.y, 32, 64));
    o.z = 0.5f * (r.z + __shfl_xor(r.z, 32, 64));
    o.w = 0.5f * (r.w + __shfl_xor(r.w, 32, 64));
    if (lane < 32) {
        float4 bb = *(const float4*)(bias + (lane << 2));
        o.x = gelu_exact(o.x + bb.x);
        o.y = gelu_exact(o.y + bb.y);
        o.z = gelu_exact(o.z + bb.z);
        o.w = gelu_exact(o.w + bb.w);
        *(float4*)(out + (size_t)v * 128 + (lane << 2)) = o;
    }
}

// ---------------------- CSR build (by dst) ---------------------------------
__global__ __launch_bounds__(256)
void hist_kernel(const int* __restrict__ ei, int* __restrict__ cnt, int E)
{
    int e = blockIdx.x * 256 + threadIdx.x;
    if (e < E) atomicAdd(&cnt[ei[E + e]], 1);
}

// stage 1: per-block (256 contiguous counts) sums via LDS Hillis-Steele
__global__ __launch_bounds__(256)
void blocksum_kernel(const int* __restrict__ cnt, int* __restrict__ bsum, int n)
{
    __shared__ int sm[256];
    const int t = threadIdx.x;
    const int i = blockIdx.x * 256 + t;
    sm[t] = (i < n) ? cnt[i] : 0;
    __syncthreads();
#pragma unroll
    for (int off = 1; off < 256; off <<= 1) {
        int u = (t >= off) ? sm[t - off] : 0;
        __syncthreads();
        sm[t] += u;
        __syncthreads();
    }
    if (t == 255) bsum[blockIdx.x] = sm[255];
}

// stage 2: single block scans block sums (nb <= 256) -> exclusive, in place
__global__ __launch_bounds__(256)
void scan_bsum_kernel(int* __restrict__ bsum, int nb, int* __restrict__ ptr, int n)
{
    __shared__ int sm[256];
    const int t = threadIdx.x;
    const int v = (t < nb) ? bsum[t] : 0;
    sm[t] = v;
    __syncthreads();
#pragma unroll
    for (int off = 1; off < 256; off <<= 1) {
        int u = (t >= off) ? sm[t - off] : 0;
        __syncthreads();
        sm[t] += u;
        __syncthreads();
    }
    if (t < nb) bsum[t] = sm[t] - v;   // exclusive prefix
    if (t == 255) ptr[n] = sm[255];    // total = E (incl. tail zeros)
}

// stage 3: block-local exclusive scan + block offset -> ptr
__global__ __launch_bounds__(256)
void scan_out_kernel(const int* __restrict__ cnt, const int* __restrict__ bsum,
                     int* __restrict__ ptr, int n)
{
    __shared__ int sm[256];
    const int t = threadIdx.x;
    const int i = blockIdx.x * 256 + t;
    const int v = (i < n) ? cnt[i] : 0;
    sm[t] = v;
    __syncthreads();
#pragma unroll
    for (int off = 1; off < 256; off <<= 1) {
        int u = (t >= off) ? sm[t - off] : 0;
        __syncthreads();
        sm[t] += u;
        __syncthreads();
    }
    if (i < n) ptr[i] = bsum[blockIdx.x] + sm[t] - v;
}

__global__ __launch_bounds__(256)
void scatter_kernel(const int* __restrict__ ei, const int* __restrict__ ptr,
                    int* __restrict__ cnt, int* __restrict__ esrc, int E)
{
    int e = blockIdx.x * 256 + threadIdx.x;
    if (e < E) {
        int dst = ei[E + e];
        int src = ei[e];
        int pos = ptr[dst] + atomicAdd(&cnt[dst], 1);
        esrc[pos] = src;
    }
}

// ---------------------------------------------------------------------------
extern "C" void kernel_launch(void* const* d_in, const int* in_sizes, int n_in,
                              void* d_out, int out_size, void* d_ws, size_t ws_size,
                              hipStream_t stream)
{
    const float* x       = (const float*)d_in[0];
    const int*   ei      = (const int*)d_in[1];
    const float* W0      = (const float*)d_in[2];
    const float* att_s0  = (const float*)d_in[3];
    const float* att_d0  = (const float*)d_in[4];
    const float* b0      = (const float*)d_in[5];
    const float* W1      = (const float*)d_in[6];
    const float* att_s1  = (const float*)d_in[7];
    const float* att_d1  = (const float*)d_in[8];
    const float* b1      = (const float*)d_in[9];
    const float* pw      = (const float*)d_in[10];
    const float* pb      = (const float*)d_in[11];

    const int N = in_sizes[0] / 256;   // 50000
    const int E = in_sizes[1] / 2;     // 800000
    const int NB = (N + 255) / 256;    // 196 scan blocks (<= 256)

    // workspace layout
    ushort* xlb = (ushort*)d_ws;                  // N*256 bf16
    float*  h   = (float*)(xlb + (size_t)N * 256);// N*128 fp32
    float*  a_s = h + (size_t)N * 128;            // N*2
    float*  a_d = a_s + (size_t)N * 2;            // N*2
    float*  wal = a_d + (size_t)N * 2;            // E*2
    float*  ndp = wal + (size_t)E * 2;            // N*4
    float*  wt0 = ndp + (size_t)N * 4;            // 256*4
    float*  wt1 = wt0 + 256 * 4;                  // 128*4
    int*    cnt = (int*)(wt1 + 128 * 4);          // N
    int*    ptr = cnt + N;                        // N+1
    int*    bsm = ptr + (N + 1);                  // NB (+pad)
    int*    esr = bsm + 256;                      // E
    ushort* w0h = (ushort*)(esr + E);             // 256*256
    ushort* w0l = w0h + 256 * 256;
    ushort* w1h = w0l + 256 * 256;                // 128*256
    ushort* w1l = w1h + 128 * 256;
    ushort* pwh = w1l + 128 * 256;                // 128*128
    ushort* pwl = pwh + 128 * 128;

    const int ablk = (N + 3) / 4;
    const int eblk = (E + 255) / 256;
    const dim3 gL0(2, (N + 127) / 128);
    const dim3 gL1(2, (N + 127) / 128);
    const dim3 gPj(1, (N + 127) / 128);

    // ---- weight prep ----
    split_w_kernel<<<(256 * 256 + 255) / 256, 256, 0, stream>>>(W0, w0h, w0l, 256, 256);
    split_w_kernel<<<(128 * 256 + 255) / 256, 256, 0, stream>>>(W1, w1h, w1l, 128, 256);
    split_w_kernel<<<(128 * 128 + 255) / 256, 256, 0, stream>>>(pw, pwh, pwl, 128, 128);
    watt_prep_kernel<<<256, 256, 0, stream>>>(W0, att_s0, att_d0, wt0, 128, 256);
    watt_prep_kernel<<<128, 256, 0, stream>>>(W1, att_s1, att_d1, wt1, 128, 256);

    // ---- CSR build ----
    hipMemsetAsync(cnt, 0, (size_t)N * sizeof(int), stream);
    hist_kernel<<<eblk, 256, 0, stream>>>(ei, cnt, E);
    blocksum_kernel<<<NB, 256, 0, stream>>>(cnt, bsm, N);
    scan_bsum_kernel<<<1, 256, 0, stream>>>(bsm, NB, ptr, N);
    scan_out_kernel<<<NB, 256, 0, stream>>>(cnt, bsm, ptr, N);
    hipMemsetAsync(cnt, 0, (size_t)N * sizeof(int), stream);
    scatter_kernel<<<eblk, 256, 0, stream>>>(ei, ptr, cnt, esr, E);

    // ---- layer 0 ----
    mfma_gemm<<<gL0, 256, 0, stream>>>(x, w0h, w0l, nullptr, nullptr, xlb, N, 256, 256);
    attn_matvec_kernel<<<ablk, 256, 0, stream>>>(x, wt0, a_s, a_d, N, 256);
    edge_alpha_kernel<<<ablk, 256, 0, stream>>>(a_s, a_d, ptr, esr, wal, ndp, N);
    gat_gather_kernel<<<ablk, 256, 0, stream>>>(xlb, ptr, esr, wal, ndp, b0, h, N);

    // ---- layer 1 ----
    mfma_gemm<<<gL1, 256, 0, stream>>>(h, w1h, w1l, nullptr, nullptr, xlb, N, 256, 128);
    attn_matvec_kernel<<<ablk, 256, 0, stream>>>(h, wt1, a_s, a_d, N, 128);
    edge_alpha_kernel<<<ablk, 256, 0, stream>>>(a_s, a_d, ptr, esr, wal, ndp, N);
    gat_gather_kernel<<<ablk, 256, 0, stream>>>(xlb, ptr, esr, wal, ndp, b1, h, N);

    // ---- projection ----
    mfma_gemm<<<gPj, 256, 0, stream>>>(h, pwh, pwl, pb, (float*)d_out, nullptr, N, 128, 128);
}